// Round 8
// baseline (282.002 us; speedup 1.0000x reference)
//
#include <hip/hip_runtime.h>
#include <math.h>

#define N_NODES 20000
#define IN_CH   512
#define HID_TOT 512   // 8 heads * 64
#define OUT_CH  256
#define N_EDGE  320000
#define TOT_EDGE (N_EDGE + N_NODES)  // 340000 incl self-loops

typedef __attribute__((ext_vector_type(8))) short short8;
typedef __attribute__((ext_vector_type(4))) float f32x4;
typedef __attribute__((ext_vector_type(2))) float f32x2;

__device__ __forceinline__ ushort f2bf(float f) {
    union { float f; unsigned u; } v; v.f = f;
    unsigned u = v.u;
    return (ushort)((u + 0x7fffu + ((u >> 16) & 1u)) >> 16);  // RNE
}
__device__ __forceinline__ float bf2f(ushort u) {
    union { unsigned u; float f; } v; v.u = ((unsigned)u) << 16; return v.f;
}

// async global->LDS, 16B per lane (m97 pattern)
__device__ __forceinline__ void glds16(const ushort* g, ushort* l) {
    __builtin_amdgcn_global_load_lds(
        (const __attribute__((address_space(1))) void*)g,
        (__attribute__((address_space(3))) void*)l, 16, 0, 0);
}

// leaky_relu(a, 0.2) == max(a, 0.2a) for all a (single VALU op)
__device__ __forceinline__ float lrelu(float a) { return fmaxf(a, 0.2f * a); }

// ------- fused prep: cast x, transpose-cast W1/W2, zero counts/as2/ad2 -----
#define NA_BLK (N_NODES * IN_CH / 4 / 256)          // 10000
#define NB_BLK ((IN_CH / 64) * (HID_TOT / 4))       // 1024
#define NC_BLK ((HID_TOT / 64) * (OUT_CH / 4))      // 512
#define NZ_BLK ((N_NODES + 255) / 256)              // 79
__global__ __launch_bounds__(256) void prep_kernel(const float* __restrict__ x,
                                                   ushort* __restrict__ xb,
                                                   const float* __restrict__ W1,
                                                   ushort* __restrict__ w1t,
                                                   const float* __restrict__ W2,
                                                   ushort* __restrict__ w2t,
                                                   int* __restrict__ counts,
                                                   float* __restrict__ as2,
                                                   float* __restrict__ ad2) {
    int b = blockIdx.x;
    int t = threadIdx.x;
    if (b < NA_BLK) {
        int i = b * 256 + t;
        float4 v = *(const float4*)&x[(size_t)i * 4];
        ushort4 o = make_ushort4(f2bf(v.x), f2bf(v.y), f2bf(v.z), f2bf(v.w));
        *(ushort4*)&xb[(size_t)i * 4] = o;
    } else if (b < NA_BLK + NB_BLK) {
        int bb = b - NA_BLK;
        int k = (bb & 7) * 64 + (t & 63);
        int n = (bb >> 3) * 4 + (t >> 6);
        w1t[(size_t)n * IN_CH + k] = f2bf(W1[(size_t)k * HID_TOT + n]);
    } else if (b < NA_BLK + NB_BLK + NC_BLK) {
        int bb = b - NA_BLK - NB_BLK;
        int k = (bb & 7) * 64 + (t & 63);
        int n = (bb >> 3) * 4 + (t >> 6);
        w2t[(size_t)n * HID_TOT + k] = f2bf(W2[(size_t)k * OUT_CH + n]);
    } else {
        int i = (b - NA_BLK - NB_BLK - NC_BLK) * 256 + t;
        if (i < N_NODES) { counts[i] = 0; as2[i] = 0.f; ad2[i] = 0.f; }
    }
}

// ---------------- CSR build (counting sort by dst) ----------------
__global__ void hist_kernel(const int* __restrict__ ei, int* __restrict__ counts) {
    int e = blockIdx.x * blockDim.x + threadIdx.x;
    if (e >= TOT_EDGE) return;
    int d = (e < N_EDGE) ? ei[N_EDGE + e] : (e - N_EDGE);
    atomicAdd(&counts[d], 1);
}

__global__ __launch_bounds__(1024) void scan_kernel(const int* __restrict__ counts,
                                                    int* __restrict__ offsets,
                                                    int* __restrict__ cursors) {
    const int C = (N_NODES + 1023) / 1024;  // 20
    int t = threadIdx.x;
    int lane = t & 63, wid = t >> 6;
    int base = t * C;
    int sum = 0;
#pragma unroll
    for (int i = 0; i < C; i++) {
        int idx = base + i;
        if (idx < N_NODES) sum += counts[idx];
    }
    int val = sum;
#pragma unroll
    for (int off = 1; off < 64; off <<= 1) {
        int y = __shfl_up(val, off);
        if (lane >= off) val += y;
    }
    __shared__ int wsum[16], woff[16], stotal;
    if (lane == 63) wsum[wid] = val;
    __syncthreads();
    if (t == 0) {
        int r = 0;
        for (int w = 0; w < 16; w++) { woff[w] = r; r += wsum[w]; }
        stotal = r;
    }
    __syncthreads();
    int running = woff[wid] + (val - sum);
#pragma unroll
    for (int i = 0; i < C; i++) {
        int idx = base + i;
        if (idx < N_NODES) {
            offsets[idx] = running;
            cursors[idx] = running;
            running += counts[idx];
        }
    }
    if (t == 0) offsets[N_NODES] = stotal;
}

__global__ void scatter_kernel(const int* __restrict__ ei, int* __restrict__ cursors,
                               int* __restrict__ srcs) {
    int e = blockIdx.x * blockDim.x + threadIdx.x;
    if (e >= TOT_EDGE) return;
    int s, d;
    if (e < N_EDGE) { s = ei[e]; d = ei[N_EDGE + e]; } else { s = e - N_EDGE; d = s; }
    int pos = atomicAdd(&cursors[d], 1);
    srcs[pos] = s;
}

// --- bf16 MFMA GEMM + fused attention-logit epilogue, fp8 h output --------
__global__ __launch_bounds__(256) void gemm_mfma_kernel(const ushort* __restrict__ A,
                                                        const ushort* __restrict__ Bt,
                                                        unsigned char* __restrict__ Cf8,
                                                        const float* __restrict__ asrc,
                                                        const float* __restrict__ adst,
                                                        float* __restrict__ as_out,
                                                        float* __restrict__ ad_out,
                                                        int M, int N, int K, int layer1) {
    __shared__ ushort As[128 * 32];
    __shared__ ushort Bs[128 * 32];
    int t = threadIdx.x;
    int lane = t & 63;
    int wave = t >> 6;
    int wm = (wave >> 1) * 64, wn = (wave & 1) * 64;
    int bm = blockIdx.y * 128, bn = blockIdx.x * 128;
    int q = lane >> 4, l15 = lane & 15;

    int c0 = t, c1 = t + 256;
    int r0 = c0 >> 2, kq0 = (c0 & 3) * 8;
    int r1 = c1 >> 2, kq1 = (c1 & 3) * 8;
    int ar0 = bm + r0; if (ar0 >= M) ar0 = M - 1;
    int ar1 = bm + r1; if (ar1 >= M) ar1 = M - 1;
    const ushort* A0 = A + (size_t)ar0 * K + kq0;
    const ushort* A1 = A + (size_t)ar1 * K + kq1;
    const ushort* B0 = Bt + (size_t)(bn + r0) * K + kq0;
    const ushort* B1 = Bt + (size_t)(bn + r1) * K + kq1;
    ushort* As0 = &As[r0 * 32 + kq0];
    ushort* As1 = &As[r1 * 32 + kq1];
    ushort* Bs0 = &Bs[r0 * 32 + kq0];
    ushort* Bs1 = &Bs[r1 * 32 + kq1];

    f32x4 acc[4][4];
#pragma unroll
    for (int i = 0; i < 4; i++)
#pragma unroll
        for (int j = 0; j < 4; j++) acc[i][j] = f32x4{0.f, 0.f, 0.f, 0.f};

    for (int k0 = 0; k0 < K; k0 += 32) {
        __syncthreads();
        glds16(A0 + k0, As0);
        glds16(A1 + k0, As1);
        glds16(B0 + k0, Bs0);
        glds16(B1 + k0, Bs1);
        __syncthreads();

        short8 af[4], bf[4];
#pragma unroll
        for (int i = 0; i < 4; i++)
            af[i] = *(const short8*)&As[(wm + i * 16 + l15) * 32 + q * 8];
#pragma unroll
        for (int j = 0; j < 4; j++)
            bf[j] = *(const short8*)&Bs[(wn + j * 16 + l15) * 32 + q * 8];
#pragma unroll
        for (int i = 0; i < 4; i++)
#pragma unroll
            for (int j = 0; j < 4; j++)
                acc[i][j] = __builtin_amdgcn_mfma_f32_16x16x32_bf16(af[i], bf[j], acc[i][j], 0, 0, 0);
    }

    // ---- fused attention logits (from fp32 acc) ----
    int colbase = bn + wn;
    float av[4], dv[4];
#pragma unroll
    for (int j = 0; j < 4; j++) {
        int cg = colbase + j * 16 + l15;
        av[j] = asrc[cg];
        dv[j] = adst[cg];
    }
    float ps[4][4], pd[4][4];
#pragma unroll
    for (int i = 0; i < 4; i++)
#pragma unroll
        for (int r = 0; r < 4; r++) {
            float p = 0.f, d = 0.f;
#pragma unroll
            for (int j = 0; j < 4; j++) {
                p = fmaf(acc[i][j][r], av[j], p);
                d = fmaf(acc[i][j][r], dv[j], d);
            }
            ps[i][r] = p; pd[i][r] = d;
        }
#pragma unroll
    for (int off = 1; off < 16; off <<= 1) {
#pragma unroll
        for (int i = 0; i < 4; i++)
#pragma unroll
            for (int r = 0; r < 4; r++) {
                ps[i][r] += __shfl_xor(ps[i][r], off);
                pd[i][r] += __shfl_xor(pd[i][r], off);
            }
    }

    // ---- C store (fp8) + logit store; C/D layout: col=lane&15, row=q*4+reg
    int hidx = colbase >> 6;
#pragma unroll
    for (int i = 0; i < 4; i++) {
#pragma unroll
        for (int r = 0; r < 4; r++) {
            int rg = bm + wm + i * 16 + q * 4 + r;
            if (rg < M) {
#pragma unroll
                for (int j = 0; j < 4; j++) {
                    int cg = colbase + j * 16 + l15;
                    int w8 = __builtin_amdgcn_cvt_pk_fp8_f32(acc[i][j][r], acc[i][j][r], 0, false);
                    Cf8[(size_t)rg * N + cg] = (unsigned char)(w8 & 0xff);
                }
                if (l15 == 0) {
                    if (layer1) {
                        as_out[rg * 8 + hidx] = ps[i][r];
                        ad_out[rg * 8 + hidx] = pd[i][r];
                    } else {
                        atomicAdd(&as_out[rg], ps[i][r]);
                        atomicAdd(&ad_out[rg], pd[i][r]);
                    }
                }
            }
        }
    }
}

// ------------- single-pass aggregation over fp8 h, 8-edge unroll ----------
// No max-subtraction (|alpha| O(1) by construction; fp32 exp overflow-safe;
// self-loops => non-empty segments). denom redundant per-thread.
// Layer 1: 64 threads/node; thread t owns channels [8t,8t+8), head h=t>>3.
__global__ __launch_bounds__(64) void agg1_kernel(const unsigned char* __restrict__ h1f,
                                                  const float* __restrict__ as1,
                                                  const float* __restrict__ ad1,
                                                  const int* __restrict__ offsets,
                                                  const int* __restrict__ srcs,
                                                  const float* __restrict__ b1,
                                                  ushort* __restrict__ h1ab) {
    int v = blockIdx.x;
    int t = threadIdx.x;
    int h = t >> 3;
    int c8 = t << 3;
    int s = offsets[v], e = offsets[v + 1];
    float adv = ad1[v * 8 + h];

    float denom = 0.f;
    float acc[8];
#pragma unroll
    for (int k = 0; k < 8; k++) acc[k] = 0.f;

    int i = s;
    for (; i + 8 <= e; i += 8) {
        int sn[8];
#pragma unroll
        for (int j = 0; j < 8; j++) sn[j] = srcs[i + j];
        uint2 r[8];
#pragma unroll
        for (int j = 0; j < 8; j++)
            r[j] = *(const uint2*)&h1f[(size_t)sn[j] * HID_TOT + c8];
        float w[8];
#pragma unroll
        for (int j = 0; j < 8; j++) {
            float a = lrelu(as1[sn[j] * 8 + h] + adv);
            w[j] = __expf(a);
            denom += w[j];
        }
#pragma unroll
        for (int j = 0; j < 8; j++) {
            f32x2 pa = __builtin_amdgcn_cvt_pk_f32_fp8(r[j].x, false);
            f32x2 pb = __builtin_amdgcn_cvt_pk_f32_fp8(r[j].x, true);
            f32x2 pc = __builtin_amdgcn_cvt_pk_f32_fp8(r[j].y, false);
            f32x2 pdd = __builtin_amdgcn_cvt_pk_f32_fp8(r[j].y, true);
            acc[0] = fmaf(w[j], pa.x, acc[0]); acc[1] = fmaf(w[j], pa.y, acc[1]);
            acc[2] = fmaf(w[j], pb.x, acc[2]); acc[3] = fmaf(w[j], pb.y, acc[3]);
            acc[4] = fmaf(w[j], pc.x, acc[4]); acc[5] = fmaf(w[j], pc.y, acc[5]);
            acc[6] = fmaf(w[j], pdd.x, acc[6]); acc[7] = fmaf(w[j], pdd.y, acc[7]);
        }
    }
    for (; i + 4 <= e; i += 4) {
        int sn[4];
#pragma unroll
        for (int j = 0; j < 4; j++) sn[j] = srcs[i + j];
        uint2 r[4];
#pragma unroll
        for (int j = 0; j < 4; j++)
            r[j] = *(const uint2*)&h1f[(size_t)sn[j] * HID_TOT + c8];
#pragma unroll
        for (int j = 0; j < 4; j++) {
            float a = lrelu(as1[sn[j] * 8 + h] + adv);
            float w = __expf(a);
            denom += w;
            f32x2 pa = __builtin_amdgcn_cvt_pk_f32_fp8(r[j].x, false);
            f32x2 pb = __builtin_amdgcn_cvt_pk_f32_fp8(r[j].x, true);
            f32x2 pc = __builtin_amdgcn_cvt_pk_f32_fp8(r[j].y, false);
            f32x2 pdd = __builtin_amdgcn_cvt_pk_f32_fp8(r[j].y, true);
            acc[0] = fmaf(w, pa.x, acc[0]); acc[1] = fmaf(w, pa.y, acc[1]);
            acc[2] = fmaf(w, pb.x, acc[2]); acc[3] = fmaf(w, pb.y, acc[3]);
            acc[4] = fmaf(w, pc.x, acc[4]); acc[5] = fmaf(w, pc.y, acc[5]);
            acc[6] = fmaf(w, pdd.x, acc[6]); acc[7] = fmaf(w, pdd.y, acc[7]);
        }
    }
    for (; i < e; i++) {
        int sn = srcs[i];
        uint2 r = *(const uint2*)&h1f[(size_t)sn * HID_TOT + c8];
        float a = lrelu(as1[sn * 8 + h] + adv);
        float w = __expf(a);
        denom += w;
        f32x2 pa = __builtin_amdgcn_cvt_pk_f32_fp8(r.x, false);
        f32x2 pb = __builtin_amdgcn_cvt_pk_f32_fp8(r.x, true);
        f32x2 pc = __builtin_amdgcn_cvt_pk_f32_fp8(r.y, false);
        f32x2 pdd = __builtin_amdgcn_cvt_pk_f32_fp8(r.y, true);
        acc[0] = fmaf(w, pa.x, acc[0]); acc[1] = fmaf(w, pa.y, acc[1]);
        acc[2] = fmaf(w, pb.x, acc[2]); acc[3] = fmaf(w, pb.y, acc[3]);
        acc[4] = fmaf(w, pc.x, acc[4]); acc[5] = fmaf(w, pc.y, acc[5]);
        acc[6] = fmaf(w, pdd.x, acc[6]); acc[7] = fmaf(w, pdd.y, acc[7]);
    }

    float inv = 1.f / (denom + 1e-16f);
    short8 ov;
#pragma unroll
    for (int k = 0; k < 8; k++) {
        float o = acc[k] * inv + b1[c8 + k];
        o = (o > 0.f) ? o : expm1f(o);
        ov[k] = (short)f2bf(o);
    }
    *(short8*)&h1ab[(size_t)v * HID_TOT + c8] = ov;
}

// Layer 2: 64 threads/node; single head; fused log_softmax; fp32 out.
__global__ __launch_bounds__(64) void agg2_kernel(const unsigned char* __restrict__ h2f,
                                                  const float* __restrict__ as2,
                                                  const float* __restrict__ ad2,
                                                  const int* __restrict__ offsets,
                                                  const int* __restrict__ srcs,
                                                  const float* __restrict__ b2,
                                                  float* __restrict__ out) {
    int v = blockIdx.x;
    int t = threadIdx.x;
    int c4 = t << 2;
    int s = offsets[v], e = offsets[v + 1];
    float adv = ad2[v];

    float denom = 0.f;
    float acc[4];
#pragma unroll
    for (int k = 0; k < 4; k++) acc[k] = 0.f;

    int i = s;
    for (; i + 8 <= e; i += 8) {
        int sn[8];
#pragma unroll
        for (int j = 0; j < 8; j++) sn[j] = srcs[i + j];
        unsigned u[8];
#pragma unroll
        for (int j = 0; j < 8; j++)
            u[j] = *(const unsigned*)&h2f[(size_t)sn[j] * OUT_CH + c4];
        float w[8];
#pragma unroll
        for (int j = 0; j < 8; j++) {
            float a = lrelu(as2[sn[j]] + adv);
            w[j] = __expf(a);
            denom += w[j];
        }
#pragma unroll
        for (int j = 0; j < 8; j++) {
            f32x2 pa = __builtin_amdgcn_cvt_pk_f32_fp8(u[j], false);
            f32x2 pb = __builtin_amdgcn_cvt_pk_f32_fp8(u[j], true);
            acc[0] = fmaf(w[j], pa.x, acc[0]); acc[1] = fmaf(w[j], pa.y, acc[1]);
            acc[2] = fmaf(w[j], pb.x, acc[2]); acc[3] = fmaf(w[j], pb.y, acc[3]);
        }
    }
    for (; i + 4 <= e; i += 4) {
        int sn[4];
#pragma unroll
        for (int j = 0; j < 4; j++) sn[j] = srcs[i + j];
        unsigned u[4];
#pragma unroll
        for (int j = 0; j < 4; j++)
            u[j] = *(const unsigned*)&h2f[(size_t)sn[j] * OUT_CH + c4];
#pragma unroll
        for (int j = 0; j < 4; j++) {
            float a = lrelu(as2[sn[j]] + adv);
            float w = __expf(a);
            denom += w;
            f32x2 pa = __builtin_amdgcn_cvt_pk_f32_fp8(u[j], false);
            f32x2 pb = __builtin_amdgcn_cvt_pk_f32_fp8(u[j], true);
            acc[0] = fmaf(w, pa.x, acc[0]); acc[1] = fmaf(w, pa.y, acc[1]);
            acc[2] = fmaf(w, pb.x, acc[2]); acc[3] = fmaf(w, pb.y, acc[3]);
        }
    }
    for (; i < e; i++) {
        int sn = srcs[i];
        unsigned u = *(const unsigned*)&h2f[(size_t)sn * OUT_CH + c4];
        float a = lrelu(as2[sn] + adv);
        float w = __expf(a);
        denom += w;
        f32x2 pa = __builtin_amdgcn_cvt_pk_f32_fp8(u, false);
        f32x2 pb = __builtin_amdgcn_cvt_pk_f32_fp8(u, true);
        acc[0] = fmaf(w, pa.x, acc[0]); acc[1] = fmaf(w, pa.y, acc[1]);
        acc[2] = fmaf(w, pb.x, acc[2]); acc[3] = fmaf(w, pb.y, acc[3]);
    }

    float inv = 1.f / (denom + 1e-16f);
    float4 bb = *(const float4*)&b2[c4];
    float4 x;
    x.x = acc[0] * inv + bb.x; x.y = acc[1] * inv + bb.y;
    x.z = acc[2] * inv + bb.z; x.w = acc[3] * inv + bb.w;

    float mm = fmaxf(fmaxf(x.x, x.y), fmaxf(x.z, x.w));
#pragma unroll
    for (int off = 1; off < 64; off <<= 1) mm = fmaxf(mm, __shfl_xor(mm, off));
    float sum = __expf(x.x - mm) + __expf(x.y - mm) + __expf(x.z - mm) + __expf(x.w - mm);
#pragma unroll
    for (int off = 1; off < 64; off <<= 1) sum += __shfl_xor(sum, off);
    float ls = logf(sum);
    float4 o;
    o.x = x.x - mm - ls; o.y = x.y - mm - ls; o.z = x.z - mm - ls; o.w = x.w - mm - ls;
    *(float4*)&out[(size_t)v * OUT_CH + c4] = o;
}

static inline size_t align256(size_t x) { return (x + 255) & ~(size_t)255; }

extern "C" void kernel_launch(void* const* d_in, const int* in_sizes, int n_in,
                              void* d_out, int out_size, void* d_ws, size_t ws_size,
                              hipStream_t stream) {
    const float* x    = (const float*)d_in[0];
    const int*   ei   = (const int*)d_in[1];
    const float* W1   = (const float*)d_in[2];
    const float* as1w = (const float*)d_in[3];
    const float* ad1w = (const float*)d_in[4];
    const float* b1   = (const float*)d_in[5];
    const float* W2   = (const float*)d_in[6];
    const float* as2w = (const float*)d_in[7];
    const float* ad2w = (const float*)d_in[8];
    const float* b2   = (const float*)d_in[9];
    float* out = (float*)d_out;

    char* p = (char*)d_ws;
    unsigned char* h1f = (unsigned char*)p; p += align256((size_t)N_NODES * HID_TOT);
    unsigned char* h2f = (unsigned char*)p; p += align256((size_t)N_NODES * OUT_CH);
    ushort* xb   = (ushort*)p; p += align256(sizeof(ushort) * (size_t)N_NODES * IN_CH);
    ushort* h1ab = xb;   // alias: xb dead after GEMM1, h1ab written after
    ushort* w1t  = (ushort*)p; p += align256(sizeof(ushort) * (size_t)IN_CH * HID_TOT);
    ushort* w2t  = (ushort*)p; p += align256(sizeof(ushort) * (size_t)HID_TOT * OUT_CH);
    float* as1  = (float*)p; p += align256(sizeof(float) * (size_t)N_NODES * 8);
    float* ad1  = (float*)p; p += align256(sizeof(float) * (size_t)N_NODES * 8);
    float* as2  = (float*)p; p += align256(sizeof(float) * (size_t)N_NODES);
    float* ad2  = (float*)p; p += align256(sizeof(float) * (size_t)N_NODES);
    int* counts  = (int*)p; p += align256(sizeof(int) * (size_t)N_NODES);
    int* offsets = (int*)p; p += align256(sizeof(int) * (size_t)(N_NODES + 1));
    int* cursors = (int*)p; p += align256(sizeof(int) * (size_t)N_NODES);
    int* srcs    = (int*)p; p += align256(sizeof(int) * (size_t)TOT_EDGE);

    prep_kernel<<<NA_BLK + NB_BLK + NC_BLK + NZ_BLK, 256, 0, stream>>>(
        x, xb, W1, w1t, W2, w2t, counts, as2, ad2);

    int eb = (TOT_EDGE + 255) / 256;
    hist_kernel<<<eb, 256, 0, stream>>>(ei, counts);
    scan_kernel<<<1, 1024, 0, stream>>>(counts, offsets, cursors);
    scatter_kernel<<<eb, 256, 0, stream>>>(ei, cursors, srcs);

    gemm_mfma_kernel<<<dim3(HID_TOT / 128, (N_NODES + 127) / 128), 256, 0, stream>>>(
        xb, w1t, h1f, as1w, ad1w, as1, ad1, N_NODES, HID_TOT, IN_CH, 1);
    agg1_kernel<<<N_NODES, 64, 0, stream>>>(h1f, as1, ad1, offsets, srcs, b1, h1ab);

    gemm_mfma_kernel<<<dim3(OUT_CH / 128, (N_NODES + 127) / 128), 256, 0, stream>>>(
        h1ab, w2t, h2f, as2w, ad2w, as2, ad2, N_NODES, OUT_CH, HID_TOT, 0);
    agg2_kernel<<<N_NODES, 64, 0, stream>>>(h2f, as2, ad2, offsets, srcs, b2, out);
}

// Round 9
// 275.272 us; speedup vs baseline: 1.0244x; 1.0244x over previous
//
#include <hip/hip_runtime.h>
#include <math.h>

#define N_NODES 20000
#define IN_CH   512
#define HID_TOT 512   // 8 heads * 64
#define OUT_CH  256
#define N_EDGE  320000
#define TOT_EDGE (N_EDGE + N_NODES)  // 340000 incl self-loops

typedef __attribute__((ext_vector_type(8))) short short8;
typedef __attribute__((ext_vector_type(4))) float f32x4;
typedef __attribute__((ext_vector_type(2))) float f32x2;

__device__ __forceinline__ ushort f2bf(float f) {
    union { float f; unsigned u; } v; v.f = f;
    unsigned u = v.u;
    return (ushort)((u + 0x7fffu + ((u >> 16) & 1u)) >> 16);  // RNE
}

// async global->LDS, 16B per lane (m97 pattern; dest = wave-uniform base + lane*16)
__device__ __forceinline__ void glds16(const ushort* g, ushort* l) {
    __builtin_amdgcn_global_load_lds(
        (const __attribute__((address_space(1))) void*)g,
        (__attribute__((address_space(3))) void*)l, 16, 0, 0);
}

// leaky_relu(a, 0.2) == max(a, 0.2a) for all a (single VALU op)
__device__ __forceinline__ float lrelu(float a) { return fmaxf(a, 0.2f * a); }

// ------- fused prep: cast x, transpose-cast W1/W2, zero counts/as2/ad2 -----
#define NA_BLK (N_NODES * IN_CH / 4 / 256)          // 10000
#define NB_BLK ((IN_CH / 64) * (HID_TOT / 4))       // 1024
#define NC_BLK ((HID_TOT / 64) * (OUT_CH / 4))      // 512
#define NZ_BLK ((N_NODES + 255) / 256)              // 79
__global__ __launch_bounds__(256) void prep_kernel(const float* __restrict__ x,
                                                   ushort* __restrict__ xb,
                                                   const float* __restrict__ W1,
                                                   ushort* __restrict__ w1t,
                                                   const float* __restrict__ W2,
                                                   ushort* __restrict__ w2t,
                                                   int* __restrict__ counts,
                                                   float* __restrict__ as2,
                                                   float* __restrict__ ad2) {
    int b = blockIdx.x;
    int t = threadIdx.x;
    if (b < NA_BLK) {
        int i = b * 256 + t;
        float4 v = *(const float4*)&x[(size_t)i * 4];
        ushort4 o = make_ushort4(f2bf(v.x), f2bf(v.y), f2bf(v.z), f2bf(v.w));
        *(ushort4*)&xb[(size_t)i * 4] = o;
    } else if (b < NA_BLK + NB_BLK) {
        int bb = b - NA_BLK;
        int k = (bb & 7) * 64 + (t & 63);
        int n = (bb >> 3) * 4 + (t >> 6);
        w1t[(size_t)n * IN_CH + k] = f2bf(W1[(size_t)k * HID_TOT + n]);
    } else if (b < NA_BLK + NB_BLK + NC_BLK) {
        int bb = b - NA_BLK - NB_BLK;
        int k = (bb & 7) * 64 + (t & 63);
        int n = (bb >> 3) * 4 + (t >> 6);
        w2t[(size_t)n * HID_TOT + k] = f2bf(W2[(size_t)k * OUT_CH + n]);
    } else {
        int i = (b - NA_BLK - NB_BLK - NC_BLK) * 256 + t;
        if (i < N_NODES) { counts[i] = 0; as2[i] = 0.f; ad2[i] = 0.f; }
    }
}

// ---------------- CSR build (counting sort by dst) ----------------
__global__ void hist_kernel(const int* __restrict__ ei, int* __restrict__ counts) {
    int e = blockIdx.x * blockDim.x + threadIdx.x;
    if (e >= TOT_EDGE) return;
    int d = (e < N_EDGE) ? ei[N_EDGE + e] : (e - N_EDGE);
    atomicAdd(&counts[d], 1);
}

__global__ __launch_bounds__(1024) void scan_kernel(const int* __restrict__ counts,
                                                    int* __restrict__ offsets,
                                                    int* __restrict__ cursors) {
    const int C = (N_NODES + 1023) / 1024;  // 20
    int t = threadIdx.x;
    int lane = t & 63, wid = t >> 6;
    int base = t * C;
    int sum = 0;
#pragma unroll
    for (int i = 0; i < C; i++) {
        int idx = base + i;
        if (idx < N_NODES) sum += counts[idx];
    }
    int val = sum;
#pragma unroll
    for (int off = 1; off < 64; off <<= 1) {
        int y = __shfl_up(val, off);
        if (lane >= off) val += y;
    }
    __shared__ int wsum[16], woff[16], stotal;
    if (lane == 63) wsum[wid] = val;
    __syncthreads();
    if (t == 0) {
        int r = 0;
        for (int w = 0; w < 16; w++) { woff[w] = r; r += wsum[w]; }
        stotal = r;
    }
    __syncthreads();
    int running = woff[wid] + (val - sum);
#pragma unroll
    for (int i = 0; i < C; i++) {
        int idx = base + i;
        if (idx < N_NODES) {
            offsets[idx] = running;
            cursors[idx] = running;
            running += counts[idx];
        }
    }
    if (t == 0) offsets[N_NODES] = stotal;
}

__global__ void scatter_kernel(const int* __restrict__ ei, int* __restrict__ cursors,
                               int* __restrict__ srcs) {
    int e = blockIdx.x * blockDim.x + threadIdx.x;
    if (e >= TOT_EDGE) return;
    int s, d;
    if (e < N_EDGE) { s = ei[e]; d = ei[N_EDGE + e]; } else { s = e - N_EDGE; d = s; }
    int pos = atomicAdd(&cursors[d], 1);
    srcs[pos] = s;
}

// --- bf16 MFMA GEMM + fused attention-logit epilogue, fp8 h output --------
// BM=128, BN=64, BK=64. 4 waves stacked in M (wave tile 32x64).
// LDS XOR swizzle: chunk (row r, slot kqs) holds global k-chunk kqs^(r&7) --
// applied on the GLOBAL side so glds16's lane*16 mapping is preserved;
// fragment reads then hit 8 distinct banks (2-way = free, m136).
// layer1: BN=64 = one head -> logits complete in-wave, direct store.
// layer2: wave covers 64 of 256 cols -> atomicAdd partials (zeroed in prep).
__global__ __launch_bounds__(256) void gemm_mfma_kernel(const ushort* __restrict__ A,
                                                        const ushort* __restrict__ Bt,
                                                        unsigned char* __restrict__ Cf8,
                                                        const float* __restrict__ asrc,
                                                        const float* __restrict__ adst,
                                                        float* __restrict__ as_out,
                                                        float* __restrict__ ad_out,
                                                        int M, int N, int K, int layer1) {
    __shared__ ushort As[128 * 64];   // 16 KB
    __shared__ ushort Bs[64 * 64];    //  8 KB
    int t = threadIdx.x;
    int lane = t & 63;
    int wave = t >> 6;
    int wm = wave * 32;
    int bm = blockIdx.y * 128, bn = blockIdx.x * 64;
    int q = lane >> 4, l15 = lane & 15;

    // staging: A chunks c = t+256k (k<4), B chunks c = t+256k (k<2)
    const ushort* Aptr[4]; ushort* Alds[4];
    const ushort* Bptr[2]; ushort* Blds[2];
#pragma unroll
    for (int k = 0; k < 4; k++) {
        int c = t + 256 * k;
        int r = c >> 3, kqs = c & 7;
        int kqg = kqs ^ (r & 7);
        int ar = bm + r; if (ar >= M) ar = M - 1;
        Aptr[k] = A + (size_t)ar * K + kqg * 8;
        Alds[k] = &As[c * 8];
    }
#pragma unroll
    for (int k = 0; k < 2; k++) {
        int c = t + 256 * k;
        int r = c >> 3, kqs = c & 7;
        int kqg = kqs ^ (r & 7);
        Bptr[k] = Bt + (size_t)(bn + r) * K + kqg * 8;
        Blds[k] = &Bs[c * 8];
    }

    f32x4 acc[2][4];
#pragma unroll
    for (int i = 0; i < 2; i++)
#pragma unroll
        for (int j = 0; j < 4; j++) acc[i][j] = f32x4{0.f, 0.f, 0.f, 0.f};

    for (int k0 = 0; k0 < K; k0 += 64) {
        __syncthreads();   // previous iteration's LDS reads done
        glds16(Aptr[0] + k0, Alds[0]);
        glds16(Aptr[1] + k0, Alds[1]);
        glds16(Aptr[2] + k0, Alds[2]);
        glds16(Aptr[3] + k0, Alds[3]);
        glds16(Bptr[0] + k0, Blds[0]);
        glds16(Bptr[1] + k0, Blds[1]);
        __syncthreads();   // drains vmcnt (async LDS writes complete)

#pragma unroll
        for (int s = 0; s < 2; s++) {
            int kq = s * 4 + q;
            short8 af[2], bf[4];
#pragma unroll
            for (int i = 0; i < 2; i++) {
                int row = wm + i * 16 + l15;
                int slot = kq ^ (row & 7);
                af[i] = *(const short8*)&As[row * 64 + slot * 8];
            }
#pragma unroll
            for (int j = 0; j < 4; j++) {
                int row = j * 16 + l15;
                int slot = kq ^ (row & 7);
                bf[j] = *(const short8*)&Bs[row * 64 + slot * 8];
            }
#pragma unroll
            for (int i = 0; i < 2; i++)
#pragma unroll
                for (int j = 0; j < 4; j++)
                    acc[i][j] = __builtin_amdgcn_mfma_f32_16x16x32_bf16(af[i], bf[j], acc[i][j], 0, 0, 0);
        }
    }

    // ---- fused attention logits (from fp32 acc) ----
    float av[4], dv[4];
#pragma unroll
    for (int j = 0; j < 4; j++) {
        int cg = bn + j * 16 + l15;
        av[j] = asrc[cg];
        dv[j] = adst[cg];
    }
    float ps[2][4], pd[2][4];
#pragma unroll
    for (int i = 0; i < 2; i++)
#pragma unroll
        for (int r = 0; r < 4; r++) {
            float p = 0.f, d = 0.f;
#pragma unroll
            for (int j = 0; j < 4; j++) {
                p = fmaf(acc[i][j][r], av[j], p);
                d = fmaf(acc[i][j][r], dv[j], d);
            }
            ps[i][r] = p; pd[i][r] = d;
        }
#pragma unroll
    for (int off = 1; off < 16; off <<= 1) {
#pragma unroll
        for (int i = 0; i < 2; i++)
#pragma unroll
            for (int r = 0; r < 4; r++) {
                ps[i][r] += __shfl_xor(ps[i][r], off);
                pd[i][r] += __shfl_xor(pd[i][r], off);
            }
    }

    // ---- C store (fp8) + logit store; C/D layout: col=lane&15, row=q*4+reg
    int hidx = blockIdx.x;   // layer1: BN=64 == one head
#pragma unroll
    for (int i = 0; i < 2; i++) {
#pragma unroll
        for (int r = 0; r < 4; r++) {
            int rg = bm + wm + i * 16 + q * 4 + r;
            if (rg < M) {
#pragma unroll
                for (int j = 0; j < 4; j++) {
                    int cg = bn + j * 16 + l15;
                    int w8 = __builtin_amdgcn_cvt_pk_fp8_f32(acc[i][j][r], acc[i][j][r], 0, false);
                    Cf8[(size_t)rg * N + cg] = (unsigned char)(w8 & 0xff);
                }
                if (l15 == 0) {
                    if (layer1) {
                        as_out[rg * 8 + hidx] = ps[i][r];
                        ad_out[rg * 8 + hidx] = pd[i][r];
                    } else {
                        atomicAdd(&as_out[rg], ps[i][r]);
                        atomicAdd(&ad_out[rg], pd[i][r]);
                    }
                }
            }
        }
    }
}

// ------------- single-pass aggregation over fp8 h, 8-edge unroll ----------
// No max-subtraction (|alpha| O(1) by construction; fp32 exp overflow-safe;
// self-loops => non-empty segments). denom redundant per-thread.
// Layer 1: 64 threads/node; thread t owns channels [8t,8t+8), head h=t>>3.
__global__ __launch_bounds__(64) void agg1_kernel(const unsigned char* __restrict__ h1f,
                                                  const float* __restrict__ as1,
                                                  const float* __restrict__ ad1,
                                                  const int* __restrict__ offsets,
                                                  const int* __restrict__ srcs,
                                                  const float* __restrict__ b1,
                                                  ushort* __restrict__ h1ab) {
    int v = blockIdx.x;
    int t = threadIdx.x;
    int h = t >> 3;
    int c8 = t << 3;
    int s = offsets[v], e = offsets[v + 1];
    float adv = ad1[v * 8 + h];

    float denom = 0.f;
    float acc[8];
#pragma unroll
    for (int k = 0; k < 8; k++) acc[k] = 0.f;

    int i = s;
    for (; i + 8 <= e; i += 8) {
        int sn[8];
#pragma unroll
        for (int j = 0; j < 8; j++) sn[j] = srcs[i + j];
        uint2 r[8];
#pragma unroll
        for (int j = 0; j < 8; j++)
            r[j] = *(const uint2*)&h1f[(size_t)sn[j] * HID_TOT + c8];
        float w[8];
#pragma unroll
        for (int j = 0; j < 8; j++) {
            float a = lrelu(as1[sn[j] * 8 + h] + adv);
            w[j] = __expf(a);
            denom += w[j];
        }
#pragma unroll
        for (int j = 0; j < 8; j++) {
            f32x2 pa = __builtin_amdgcn_cvt_pk_f32_fp8(r[j].x, false);
            f32x2 pb = __builtin_amdgcn_cvt_pk_f32_fp8(r[j].x, true);
            f32x2 pc = __builtin_amdgcn_cvt_pk_f32_fp8(r[j].y, false);
            f32x2 pdd = __builtin_amdgcn_cvt_pk_f32_fp8(r[j].y, true);
            acc[0] = fmaf(w[j], pa.x, acc[0]); acc[1] = fmaf(w[j], pa.y, acc[1]);
            acc[2] = fmaf(w[j], pb.x, acc[2]); acc[3] = fmaf(w[j], pb.y, acc[3]);
            acc[4] = fmaf(w[j], pc.x, acc[4]); acc[5] = fmaf(w[j], pc.y, acc[5]);
            acc[6] = fmaf(w[j], pdd.x, acc[6]); acc[7] = fmaf(w[j], pdd.y, acc[7]);
        }
    }
    for (; i + 4 <= e; i += 4) {
        int sn[4];
#pragma unroll
        for (int j = 0; j < 4; j++) sn[j] = srcs[i + j];
        uint2 r[4];
#pragma unroll
        for (int j = 0; j < 4; j++)
            r[j] = *(const uint2*)&h1f[(size_t)sn[j] * HID_TOT + c8];
#pragma unroll
        for (int j = 0; j < 4; j++) {
            float a = lrelu(as1[sn[j] * 8 + h] + adv);
            float w = __expf(a);
            denom += w;
            f32x2 pa = __builtin_amdgcn_cvt_pk_f32_fp8(r[j].x, false);
            f32x2 pb = __builtin_amdgcn_cvt_pk_f32_fp8(r[j].x, true);
            f32x2 pc = __builtin_amdgcn_cvt_pk_f32_fp8(r[j].y, false);
            f32x2 pdd = __builtin_amdgcn_cvt_pk_f32_fp8(r[j].y, true);
            acc[0] = fmaf(w, pa.x, acc[0]); acc[1] = fmaf(w, pa.y, acc[1]);
            acc[2] = fmaf(w, pb.x, acc[2]); acc[3] = fmaf(w, pb.y, acc[3]);
            acc[4] = fmaf(w, pc.x, acc[4]); acc[5] = fmaf(w, pc.y, acc[5]);
            acc[6] = fmaf(w, pdd.x, acc[6]); acc[7] = fmaf(w, pdd.y, acc[7]);
        }
    }
    for (; i < e; i++) {
        int sn = srcs[i];
        uint2 r = *(const uint2*)&h1f[(size_t)sn * HID_TOT + c8];
        float a = lrelu(as1[sn * 8 + h] + adv);
        float w = __expf(a);
        denom += w;
        f32x2 pa = __builtin_amdgcn_cvt_pk_f32_fp8(r.x, false);
        f32x2 pb = __builtin_amdgcn_cvt_pk_f32_fp8(r.x, true);
        f32x2 pc = __builtin_amdgcn_cvt_pk_f32_fp8(r.y, false);
        f32x2 pdd = __builtin_amdgcn_cvt_pk_f32_fp8(r.y, true);
        acc[0] = fmaf(w, pa.x, acc[0]); acc[1] = fmaf(w, pa.y, acc[1]);
        acc[2] = fmaf(w, pb.x, acc[2]); acc[3] = fmaf(w, pb.y, acc[3]);
        acc[4] = fmaf(w, pc.x, acc[4]); acc[5] = fmaf(w, pc.y, acc[5]);
        acc[6] = fmaf(w, pdd.x, acc[6]); acc[7] = fmaf(w, pdd.y, acc[7]);
    }

    float inv = 1.f / (denom + 1e-16f);
    short8 ov;
#pragma unroll
    for (int k = 0; k < 8; k++) {
        float o = acc[k] * inv + b1[c8 + k];
        o = (o > 0.f) ? o : expm1f(o);
        ov[k] = (short)f2bf(o);
    }
    *(short8*)&h1ab[(size_t)v * HID_TOT + c8] = ov;
}

// Layer 2: 64 threads/node; single head; fused log_softmax; fp32 out.
__global__ __launch_bounds__(64) void agg2_kernel(const unsigned char* __restrict__ h2f,
                                                  const float* __restrict__ as2,
                                                  const float* __restrict__ ad2,
                                                  const int* __restrict__ offsets,
                                                  const int* __restrict__ srcs,
                                                  const float* __restrict__ b2,
                                                  float* __restrict__ out) {
    int v = blockIdx.x;
    int t = threadIdx.x;
    int c4 = t << 2;
    int s = offsets[v], e = offsets[v + 1];
    float adv = ad2[v];

    float denom = 0.f;
    float acc[4];
#pragma unroll
    for (int k = 0; k < 4; k++) acc[k] = 0.f;

    int i = s;
    for (; i + 8 <= e; i += 8) {
        int sn[8];
#pragma unroll
        for (int j = 0; j < 8; j++) sn[j] = srcs[i + j];
        unsigned u[8];
#pragma unroll
        for (int j = 0; j < 8; j++)
            u[j] = *(const unsigned*)&h2f[(size_t)sn[j] * OUT_CH + c4];
        float w[8];
#pragma unroll
        for (int j = 0; j < 8; j++) {
            float a = lrelu(as2[sn[j]] + adv);
            w[j] = __expf(a);
            denom += w[j];
        }
#pragma unroll
        for (int j = 0; j < 8; j++) {
            f32x2 pa = __builtin_amdgcn_cvt_pk_f32_fp8(u[j], false);
            f32x2 pb = __builtin_amdgcn_cvt_pk_f32_fp8(u[j], true);
            acc[0] = fmaf(w[j], pa.x, acc[0]); acc[1] = fmaf(w[j], pa.y, acc[1]);
            acc[2] = fmaf(w[j], pb.x, acc[2]); acc[3] = fmaf(w[j], pb.y, acc[3]);
        }
    }
    for (; i + 4 <= e; i += 4) {
        int sn[4];
#pragma unroll
        for (int j = 0; j < 4; j++) sn[j] = srcs[i + j];
        unsigned u[4];
#pragma unroll
        for (int j = 0; j < 4; j++)
            u[j] = *(const unsigned*)&h2f[(size_t)sn[j] * OUT_CH + c4];
#pragma unroll
        for (int j = 0; j < 4; j++) {
            float a = lrelu(as2[sn[j]] + adv);
            float w = __expf(a);
            denom += w;
            f32x2 pa = __builtin_amdgcn_cvt_pk_f32_fp8(u[j], false);
            f32x2 pb = __builtin_amdgcn_cvt_pk_f32_fp8(u[j], true);
            acc[0] = fmaf(w, pa.x, acc[0]); acc[1] = fmaf(w, pa.y, acc[1]);
            acc[2] = fmaf(w, pb.x, acc[2]); acc[3] = fmaf(w, pb.y, acc[3]);
        }
    }
    for (; i < e; i++) {
        int sn = srcs[i];
        unsigned u = *(const unsigned*)&h2f[(size_t)sn * OUT_CH + c4];
        float a = lrelu(as2[sn] + adv);
        float w = __expf(a);
        denom += w;
        f32x2 pa = __builtin_amdgcn_cvt_pk_f32_fp8(u, false);
        f32x2 pb = __builtin_amdgcn_cvt_pk_f32_fp8(u, true);
        acc[0] = fmaf(w, pa.x, acc[0]); acc[1] = fmaf(w, pa.y, acc[1]);
        acc[2] = fmaf(w, pb.x, acc[2]); acc[3] = fmaf(w, pb.y, acc[3]);
    }

    float inv = 1.f / (denom + 1e-16f);
    float4 bb = *(const float4*)&b2[c4];
    float4 x;
    x.x = acc[0] * inv + bb.x; x.y = acc[1] * inv + bb.y;
    x.z = acc[2] * inv + bb.z; x.w = acc[3] * inv + bb.w;

    float mm = fmaxf(fmaxf(x.x, x.y), fmaxf(x.z, x.w));
#pragma unroll
    for (int off = 1; off < 64; off <<= 1) mm = fmaxf(mm, __shfl_xor(mm, off));
    float sum = __expf(x.x - mm) + __expf(x.y - mm) + __expf(x.z - mm) + __expf(x.w - mm);
#pragma unroll
    for (int off = 1; off < 64; off <<= 1) sum += __shfl_xor(sum, off);
    float ls = logf(sum);
    float4 o;
    o.x = x.x - mm - ls; o.y = x.y - mm - ls; o.z = x.z - mm - ls; o.w = x.w - mm - ls;
    *(float4*)&out[(size_t)v * OUT_CH + c4] = o;
}

static inline size_t align256(size_t x) { return (x + 255) & ~(size_t)255; }

extern "C" void kernel_launch(void* const* d_in, const int* in_sizes, int n_in,
                              void* d_out, int out_size, void* d_ws, size_t ws_size,
                              hipStream_t stream) {
    const float* x    = (const float*)d_in[0];
    const int*   ei   = (const int*)d_in[1];
    const float* W1   = (const float*)d_in[2];
    const float* as1w = (const float*)d_in[3];
    const float* ad1w = (const float*)d_in[4];
    const float* b1   = (const float*)d_in[5];
    const float* W2   = (const float*)d_in[6];
    const float* as2w = (const float*)d_in[7];
    const float* ad2w = (const float*)d_in[8];
    const float* b2   = (const float*)d_in[9];
    float* out = (float*)d_out;

    char* p = (char*)d_ws;
    unsigned char* h1f = (unsigned char*)p; p += align256((size_t)N_NODES * HID_TOT);
    unsigned char* h2f = (unsigned char*)p; p += align256((size_t)N_NODES * OUT_CH);
    ushort* xb   = (ushort*)p; p += align256(sizeof(ushort) * (size_t)N_NODES * IN_CH);
    ushort* h1ab = xb;   // alias: xb dead after GEMM1, h1ab written after
    ushort* w1t  = (ushort*)p; p += align256(sizeof(ushort) * (size_t)IN_CH * HID_TOT);
    ushort* w2t  = (ushort*)p; p += align256(sizeof(ushort) * (size_t)HID_TOT * OUT_CH);
    float* as1  = (float*)p; p += align256(sizeof(float) * (size_t)N_NODES * 8);
    float* ad1  = (float*)p; p += align256(sizeof(float) * (size_t)N_NODES * 8);
    float* as2  = (float*)p; p += align256(sizeof(float) * (size_t)N_NODES);
    float* ad2  = (float*)p; p += align256(sizeof(float) * (size_t)N_NODES);
    int* counts  = (int*)p; p += align256(sizeof(int) * (size_t)N_NODES);
    int* offsets = (int*)p; p += align256(sizeof(int) * (size_t)(N_NODES + 1));
    int* cursors = (int*)p; p += align256(sizeof(int) * (size_t)N_NODES);
    int* srcs    = (int*)p; p += align256(sizeof(int) * (size_t)TOT_EDGE);

    prep_kernel<<<NA_BLK + NB_BLK + NC_BLK + NZ_BLK, 256, 0, stream>>>(
        x, xb, W1, w1t, W2, w2t, counts, as2, ad2);

    int eb = (TOT_EDGE + 255) / 256;
    hist_kernel<<<eb, 256, 0, stream>>>(ei, counts);
    scan_kernel<<<1, 1024, 0, stream>>>(counts, offsets, cursors);
    scatter_kernel<<<eb, 256, 0, stream>>>(ei, cursors, srcs);

    gemm_mfma_kernel<<<dim3(HID_TOT / 64, (N_NODES + 127) / 128), 256, 0, stream>>>(
        xb, w1t, h1f, as1w, ad1w, as1, ad1, N_NODES, HID_TOT, IN_CH, 1);
    agg1_kernel<<<N_NODES, 64, 0, stream>>>(h1f, as1, ad1, offsets, srcs, b1, h1ab);

    gemm_mfma_kernel<<<dim3(OUT_CH / 64, (N_NODES + 127) / 128), 256, 0, stream>>>(
        h1ab, w2t, h2f, as2w, ad2w, as2, ad2, N_NODES, OUT_CH, HID_TOT, 0);
    agg2_kernel<<<N_NODES, 64, 0, stream>>>(h2f, as2, ad2, offsets, srcs, b2, out);
}